// Round 17
// baseline (202.997 us; speedup 1.0000x reference)
//
#include <hip/hip_runtime.h>

// Problem dims
#define LL 1024
#define BB 8
#define EE 1024
#define HH 16
#define HD 64
#define MROWS (LL*BB)   // 8192 token rows

typedef __attribute__((ext_vector_type(8))) short short8v;   // 8 bf16 (4 VGPRs)
typedef __attribute__((ext_vector_type(4))) float f32x4;
typedef __attribute__((ext_vector_type(16))) float f32x16;

#define LOG2E 1.44269504088896f

__device__ __forceinline__ unsigned short tobf(float f) {
    union { float f; unsigned u; } un; un.f = f;
    unsigned u = un.u;
    u += 0x7fffu + ((u >> 16) & 1u);   // round-to-nearest-even
    return (unsigned short)(u >> 16);
}

__device__ __forceinline__ float max3f(float a, float b, float c) {
    return fmaxf(fmaxf(a, b), c);      // clang fuses to v_max3_f32
}

__device__ __forceinline__ void load_lds16(const unsigned short* g, unsigned short* l) {
    // async global->LDS, 16B per lane; LDS dest = wave-uniform base + lane*16
    __builtin_amdgcn_global_load_lds((const __attribute__((address_space(1))) unsigned int*)g,
                                     (__attribute__((address_space(3))) unsigned int*)l,
                                     16, 0, 0);
}

// ---------------- weight f32 -> bf16, 4 weights in one launch -----------------
__global__ __launch_bounds__(256) void convw4_kernel(const float* __restrict__ w0,
                                                     const float* __restrict__ w1,
                                                     const float* __restrict__ w2,
                                                     const float* __restrict__ w3,
                                                     unsigned short* __restrict__ o0,
                                                     unsigned short* __restrict__ o1,
                                                     unsigned short* __restrict__ o2,
                                                     unsigned short* __restrict__ o3) {
    const float* w; unsigned short* o;
    switch (blockIdx.y) {
        case 0:  w = w0; o = o0; break;
        case 1:  w = w1; o = o1; break;
        case 2:  w = w2; o = o2; break;
        default: w = w3; o = o3; break;
    }
    int i = (blockIdx.x * 256 + threadIdx.x) * 4;
    float4 v = *(const float4*)&w[i];
    ushort4 r;
    r.x = tobf(v.x); r.y = tobf(v.y); r.z = tobf(v.z); r.w = tobf(v.w);
    *(ushort4*)&o[i] = r;
}

// ---------------- mask prep: maskT2[k2][q] = pack(bf16(mask[q][2k2]*log2e),
//  bf16(mask[q][2k2+1]*log2e)) transposed pair-packed; OR-reduce nonzero flag --
__global__ __launch_bounds__(256) void maskprep_kernel(const float* __restrict__ m,
                                                       unsigned* __restrict__ o,
                                                       unsigned* __restrict__ flag) {
    __shared__ float t_sh[64][65];
    const int q0 = blockIdx.x * 64, k0 = blockIdx.y * 64;
    const int tid = threadIdx.x;
    unsigned nz = 0;
    {
        const int r = tid >> 2, c0 = (tid & 3) * 16;
        #pragma unroll
        for (int i = 0; i < 4; ++i) {
            float4 v = *(const float4*)&m[(size_t)(q0 + r) * LL + k0 + c0 + i*4];
            nz |= (v.x != 0.0f) | (v.y != 0.0f) | (v.z != 0.0f) | (v.w != 0.0f);
            t_sh[r][c0+i*4+0] = v.x; t_sh[r][c0+i*4+1] = v.y;
            t_sh[r][c0+i*4+2] = v.z; t_sh[r][c0+i*4+3] = v.w;
        }
    }
    if (__any(nz) && (tid & 63) == 0) atomicOr(flag, 1u);
    __syncthreads();
    const int k2l = tid >> 3, qi = (tid & 7) * 8;
    unsigned pk[8];
    #pragma unroll
    for (int j = 0; j < 8; ++j) {
        const unsigned lo = tobf(t_sh[qi+j][2*k2l]   * LOG2E);
        const unsigned hb = tobf(t_sh[qi+j][2*k2l+1] * LOG2E);
        pk[j] = lo | (hb << 16);
    }
    unsigned* orow = &o[(size_t)(k0/2 + k2l) * LL + q0 + qi];
    *(uint4*)&orow[0] = make_uint4(pk[0], pk[1], pk[2], pk[3]);
    *(uint4*)&orow[4] = make_uint4(pk[4], pk[5], pk[6], pk[7]);
}

// ---------------- LayerNorm: (L,B,E) in -> (B,L,E) out (token-major rows) ----
__global__ __launch_bounds__(256) void ln_kernel(const float* __restrict__ x,
                                                 const float* __restrict__ gamma,
                                                 const float* __restrict__ beta,
                                                 unsigned short* __restrict__ out) {
    const int row = blockIdx.x;              // (L,B) row: l = row>>3, b = row&7
    const int tid = threadIdx.x;
    const float4 v = *(const float4*)&x[(size_t)row * EE + tid * 4];
    float s = v.x + v.y + v.z + v.w;
    float q = v.x*v.x + v.y*v.y + v.z*v.z + v.w*v.w;
    #pragma unroll
    for (int off = 1; off < 64; off <<= 1) {
        s += __shfl_xor(s, off);
        q += __shfl_xor(q, off);
    }
    __shared__ float ss[4], sq[4];
    const int wv = tid >> 6;
    if ((tid & 63) == 0) { ss[wv] = s; sq[wv] = q; }
    __syncthreads();
    s = ss[0] + ss[1] + ss[2] + ss[3];
    q = sq[0] + sq[1] + sq[2] + sq[3];
    const float mu = s * (1.0f / EE);
    const float var = q * (1.0f / EE) - mu * mu;
    const float rs = rsqrtf(var + 1e-5f);
    ushort4 o;
    o.x = tobf((v.x - mu) * rs * gamma[tid*4+0] + beta[tid*4+0]);
    o.y = tobf((v.y - mu) * rs * gamma[tid*4+1] + beta[tid*4+1]);
    o.z = tobf((v.z - mu) * rs * gamma[tid*4+2] + beta[tid*4+2]);
    o.w = tobf((v.w - mu) * rs * gamma[tid*4+3] + beta[tid*4+3]);
    const int rowBL = (row & 7) * LL + (row >> 3);   // (B,L) row order
    *(ushort4*)&out[(size_t)rowBL * EE + tid * 4] = o;
}

// ---------------- 128x128-tile GEMM, BK=32, 3-buffer counted-vmcnt (gemm_o) ---
#define GEMM128_BODY(A_, W_)                                                              \
    __shared__ unsigned short a_sh[3][128*32];                                            \
    __shared__ unsigned short b_sh[3][128*32];                                            \
    const int tid = threadIdx.x, lane = tid & 63, wave = tid >> 6;                        \
    const int bm = blockIdx.y * 128, bn = blockIdx.x * 128;                               \
    const int wr = (wave >> 1) * 64, wc = (wave & 1) * 64;                                \
    const int l16 = lane & 15, q4 = lane >> 4;                                            \
    const int grow = lane >> 2;                                                           \
    const int gswz = (((lane & 3) ^ ((lane >> 4) & 3)) * 8);                              \
    const int rslot = (q4 ^ ((l16 >> 2) & 3)) * 16;  /* ds_read byte slot */              \
    f32x4 acc[4][4] = {};                                                                 \
    _Pragma("unroll")                                                                     \
    for (int i = 0; i < 2; ++i) {                                                         \
        const int ch = wave * 2 + i;                                                      \
        load_lds16(&A_[(size_t)(bm + ch*16 + grow)*EE + gswz], &a_sh[0][ch*512]);         \
        load_lds16(&W_[(size_t)(bn + ch*16 + grow)*EE + gswz], &b_sh[0][ch*512]);         \
    }                                                                                     \
    _Pragma("unroll")                                                                     \
    for (int i = 0; i < 2; ++i) {                                                         \
        const int ch = wave * 2 + i;                                                      \
        load_lds16(&A_[(size_t)(bm + ch*16 + grow)*EE + 32 + gswz], &a_sh[1][ch*512]);    \
        load_lds16(&W_[(size_t)(bn + ch*16 + grow)*EE + 32 + gswz], &b_sh[1][ch*512]);    \
    }                                                                                     \
    int buf = 0, sb = 2;                                                                  \
    for (int it = 0; it < 32; ++it) {                                                     \
        if (it < 31) asm volatile("s_waitcnt vmcnt(4)" ::: "memory");                     \
        else         asm volatile("s_waitcnt vmcnt(0)" ::: "memory");                     \
        __builtin_amdgcn_s_barrier();                                                     \
        if (it < 30) {                                                                    \
            const int kn = (it + 2) * 32;                                                 \
            _Pragma("unroll")                                                             \
            for (int i = 0; i < 2; ++i) {                                                 \
                const int ch = wave * 2 + i;                                              \
                load_lds16(&A_[(size_t)(bm + ch*16 + grow)*EE + kn + gswz], &a_sh[sb][ch*512]); \
                load_lds16(&W_[(size_t)(bn + ch*16 + grow)*EE + kn + gswz], &b_sh[sb][ch*512]); \
            }                                                                             \
        }                                                                                 \
        short8v af[4], bf[4];                                                             \
        _Pragma("unroll")                                                                 \
        for (int mi = 0; mi < 4; ++mi)                                                    \
            af[mi] = *(const short8v*)((const char*)&a_sh[buf][0] + (size_t)(wr + mi*16 + l16)*64 + rslot); \
        _Pragma("unroll")                                                                 \
        for (int ni = 0; ni < 4; ++ni)                                                    \
            bf[ni] = *(const short8v*)((const char*)&b_sh[buf][0] + (size_t)(wc + ni*16 + l16)*64 + rslot); \
        __builtin_amdgcn_s_setprio(1);                                                    \
        _Pragma("unroll")                                                                 \
        for (int mi = 0; mi < 4; ++mi)                                                    \
            _Pragma("unroll")                                                             \
            for (int ni = 0; ni < 4; ++ni)                                                \
                acc[mi][ni] = __builtin_amdgcn_mfma_f32_16x16x32_bf16(af[mi], bf[ni], acc[mi][ni], 0, 0, 0); \
        __builtin_amdgcn_s_setprio(0);                                                    \
        buf = (buf == 2) ? 0 : buf + 1;                                                   \
        sb  = (sb  == 2) ? 0 : sb  + 1;                                                   \
    }

// QKV fused: 128x256 tile (BN=256 doubles MFMA per barrier epoch; same 3-buffer
// counted-vmcnt ledger scaled to 6 loads/tile/wave -> vmcnt(6)). 1-D grid of
// 768 blocks, XCD-chunked (768%8==0): each XCD owns 8 contiguous A-panels.
// A in (B,L,E); epilogue scatters Q/K/V into MFMA-fragment layouts.
__global__ __launch_bounds__(256, 2) void gemm_qkv(const unsigned short* __restrict__ A,
                                                   const unsigned short* __restrict__ W,
                                                   const float* __restrict__ bq,
                                                   const float* __restrict__ bk,
                                                   const float* __restrict__ bv,
                                                   unsigned short* __restrict__ qo,
                                                   unsigned short* __restrict__ ko,
                                                   unsigned short* __restrict__ vo) {
    __shared__ unsigned short a_sh[3][128*32];   // 8 KB x3
    __shared__ unsigned short b_sh[3][256*32];   // 16 KB x3
    const int tid = threadIdx.x, lane = tid & 63, wave = tid >> 6;
    const int id  = (blockIdx.x & 7) * 96 + (blockIdx.x >> 3);   // XCD-chunked
    const int bm  = (id / 12) * 128, bn = (id % 12) * 256;
    const int wr = (wave >> 1) * 64, wc = (wave & 1) * 128;
    const int l16 = lane & 15, q4 = lane >> 4;
    const int grow = lane >> 2;
    const int gswz = (((lane & 3) ^ ((lane >> 4) & 3)) * 8);
    const int rslot = (q4 ^ ((l16 >> 2) & 3)) * 16;

    auto stageA = [&](int d, int k0) {
        #pragma unroll
        for (int i = 0; i < 2; ++i) {
            const int ch = wave * 2 + i;            // 8 chunks of 16 rows
            load_lds16(&A[(size_t)(bm + ch*16 + grow)*EE + k0 + gswz], &a_sh[d][ch*512]);
        }
    };
    auto stageB = [&](int d, int k0) {
        #pragma unroll
        for (int i = 0; i < 4; ++i) {
            const int ch = wave * 4 + i;            // 16 chunks of 16 rows
            load_lds16(&W[(size_t)(bn + ch*16 + grow)*EE + k0 + gswz], &b_sh[d][ch*512]);
        }
    };

    f32x4 acc[4][8] = {};
    stageA(0, 0);  stageB(0, 0);
    stageA(1, 32); stageB(1, 32);
    int buf = 0, sb = 2;
    for (int it = 0; it < 32; ++it) {
        if (it < 31) asm volatile("s_waitcnt vmcnt(6)" ::: "memory");
        else         asm volatile("s_waitcnt vmcnt(0)" ::: "memory");
        __builtin_amdgcn_s_barrier();
        if (it < 30) { stageA(sb, (it + 2) * 32); stageB(sb, (it + 2) * 32); }
        short8v af[4], bf[8];
        #pragma unroll
        for (int mi = 0; mi < 4; ++mi)
            af[mi] = *(const short8v*)((const char*)&a_sh[buf][0]
                        + (size_t)(wr + mi*16 + l16)*64 + rslot);
        #pragma unroll
        for (int ni = 0; ni < 8; ++ni)
            bf[ni] = *(const short8v*)((const char*)&b_sh[buf][0]
                        + (size_t)(wc + ni*16 + l16)*64 + rslot);
        __builtin_amdgcn_s_setprio(1);
        #pragma unroll
        for (int mi = 0; mi < 4; ++mi)
            #pragma unroll
            for (int ni = 0; ni < 8; ++ni)
                acc[mi][ni] = __builtin_amdgcn_mfma_f32_16x16x32_bf16(af[mi], bf[ni], acc[mi][ni], 0, 0, 0);
        __builtin_amdgcn_s_setprio(0);
        buf = (buf == 2) ? 0 : buf + 1;
        sb  = (sb  == 2) ? 0 : sb  + 1;
    }
    // epilogue: seg uniform (256 | 1024)
    const int seg = bn >> 10;
    const float* bias = seg == 0 ? bq : (seg == 1 ? bk : bv);
    #pragma unroll
    for (int mi = 0; mi < 4; ++mi) {
        #pragma unroll
        for (int ni = 0; ni < 8; ++ni) {
            if (seg == 2) {
                // V: pack r=0..3 (consecutive tokens -> consecutive ke) into 8B
                const int m0    = bm + wr + mi*16 + (lane >> 4)*4;
                const int token = m0 & 1023, b = m0 >> 10;
                const int nn = (bn & 1023) + wc + ni*16 + l16;
                const int d = nn & 63, h = nn >> 6;
                const int bh = b*HH + h;
                const int k16 = token >> 4, khi = (token >> 3) & 1, ke0 = token & 7;
                const int dt = d >> 5, dl = d & 31;
                const float bs = bias[nn];
                ushort4 pk;
                pk.x = tobf(acc[mi][ni][0] + bs);
                pk.y = tobf(acc[mi][ni][1] + bs);
                pk.z = tobf(acc[mi][ni][2] + bs);
                pk.w = tobf(acc[mi][ni][3] + bs);
                *(ushort4*)&vo[((((size_t)bh*64 + k16)*2 + dt)*64 + khi*32 + dl)*8 + ke0] = pk;
            } else {
                #pragma unroll
                for (int r = 0; r < 4; ++r) {
                    const int m  = bm + wr + mi*16 + (lane >> 4)*4 + r;
                    const int token = m & 1023, b = m >> 10;
                    const int nn = (bn & 1023) + wc + ni*16 + l16;
                    const float v = acc[mi][ni][r] + bias[nn];
                    const int d = nn & 63, h = nn >> 6;
                    const int bh = b*HH + h;
                    const int t32 = token >> 5, l32 = token & 31;
                    const int dc = d >> 4, hi2 = (d >> 3) & 1, e = d & 7;
                    const size_t idx = ((((size_t)bh*32 + t32)*4 + dc)*64 + hi2*32 + l32)*8 + e;
                    if (seg == 0) qo[idx] = tobf(v * (0.125f * LOG2E));  // exp2-domain Q
                    else          ko[idx] = tobf(v);
                }
            }
        }
    }
}

// Output projection + bias + residual; A (=attnb) in (B,L,E), out/xres in (L,B,E).
__global__ __launch_bounds__(256) void gemm_o(const unsigned short* __restrict__ A,
                                              const unsigned short* __restrict__ W,
                                              const float* __restrict__ bias,
                                              const float* __restrict__ xres,
                                              float* __restrict__ outf) {
    GEMM128_BODY(A, W)
    #pragma unroll
    for (int mi = 0; mi < 4; ++mi) {
        #pragma unroll
        for (int ni = 0; ni < 4; ++ni) {
            #pragma unroll
            for (int r = 0; r < 4; ++r) {
                const int m = bm + wr + mi*16 + (lane >> 4)*4 + r;   // (B,L) row
                const int token = m & 1023, b = m >> 10;
                const int mout = token * BB + b;                      // (L,B) row
                const int n = bn + wc + ni*16 + l16;
                outf[(size_t)mout * EE + n] = acc[mi][ni][r] + bias[n] + xres[(size_t)mout * EE + n];
            }
        }
    }
}

// ---------------- Flash attention: LDS-free, round-9 structure (verified) ----
__global__ __launch_bounds__(256, 4) void attn_kernel(const unsigned short* __restrict__ Qf,
                                                      const unsigned short* __restrict__ Kf,
                                                      const unsigned short* __restrict__ Vf,
                                                      const unsigned* __restrict__ maskT2,
                                                      const unsigned* __restrict__ mflagp,
                                                      unsigned short* __restrict__ attn_out) {
    const int tid = threadIdx.x, lane = tid & 63, wave = tid >> 6;
    const int l32 = lane & 31, hi = lane >> 5;
    const int b1 = blockIdx.x;
    const int bh = (b1 & 7) * 16 + ((b1 >> 3) & 15);   // all 8 blocks of bh -> same XCD
    const int qt = ((b1 >> 7) & 7) * 4 + wave;          // 32-token q tile
    const int qtok = qt * 32 + l32;
    const unsigned mf = (unsigned)__builtin_amdgcn_readfirstlane((int)mflagp[0]);
    const unsigned short* qfp = Qf + ((size_t)(bh * 32 + qt) * 4) * 512;
    const unsigned short* kfb = Kf + (size_t)bh * 32 * 4 * 512;
    const unsigned short* vfb = Vf + (size_t)bh * 64 * 2 * 512;

    short8v qf[4];
    #pragma unroll
    for (int dc = 0; dc < 4; ++dc)
        qf[dc] = *(const short8v*)&qfp[dc * 512 + lane * 8];

    f32x16 acc[2] = {};           // O^T accumulator: dt=0 (d 0..31), dt=1 (d 32..63)
    float mrun = -1e30f, srun = 0.f;

    const unsigned* mt2base = maskT2 + qtok;
    short8v kf[4];
    #pragma unroll
    for (int dc = 0; dc < 4; ++dc)
        kf[dc] = *(const short8v*)&kfb[dc * 512 + lane * 8];
    unsigned mcur[8], mnxt[8];
    if (mf) {
        #pragma unroll
        for (int j = 0; j < 8; ++j)
            mcur[j] = mt2base[(size_t)((j & 1) + 4*(j >> 1) + 2*hi) * LL];
    }

    for (int t = 0; t < 32; ++t) {
        // ---- S^T = K . Q^T over d=64 (4 chained mfma) ----
        f32x16 s = {};
        __builtin_amdgcn_s_setprio(1);
        #pragma unroll
        for (int dc = 0; dc < 4; ++dc)
            s = __builtin_amdgcn_mfma_f32_32x32x16_bf16(kf[dc], qf[dc], s, 0, 0, 0);
        __builtin_amdgcn_s_setprio(0);
        // ---- prefetch: this tile's V frags, next tile's K frags + mask ----
        short8v vf00, vf01, vf10, vf11;   // [ks][dt]
        vf00 = *(const short8v*)&vfb[((size_t)(t*2 + 0)*2 + 0)*512 + lane*8];
        vf01 = *(const short8v*)&vfb[((size_t)(t*2 + 0)*2 + 1)*512 + lane*8];
        vf10 = *(const short8v*)&vfb[((size_t)(t*2 + 1)*2 + 0)*512 + lane*8];
        vf11 = *(const short8v*)&vfb[((size_t)(t*2 + 1)*2 + 1)*512 + lane*8];
        if (t < 31) {
            #pragma unroll
            for (int dc = 0; dc < 4; ++dc)
                kf[dc] = *(const short8v*)&kfb[((size_t)(t + 1)*4 + dc)*512 + lane*8];
            if (mf) {
                #pragma unroll
                for (int j = 0; j < 8; ++j)
                    mnxt[j] = mt2base[(size_t)((t + 1)*16 + (j & 1) + 4*(j >> 1) + 2*hi) * LL];
            }
        }
        // ---- mask add (skipped entirely when mask is all-zero) ----
        if (mf) {
            #pragma unroll
            for (int j = 0; j < 8; ++j) {
                s[2*j]   += __uint_as_float(mcur[j] << 16);
                s[2*j+1] += __uint_as_float(mcur[j] & 0xffff0000u);
            }
        }
        // ---- max (tree + cross-half shfl) ----
        const float a0 = max3f(s[0],  s[1],  s[2]);
        const float a1 = max3f(s[3],  s[4],  s[5]);
        const float a2 = max3f(s[6],  s[7],  s[8]);
        const float a3 = max3f(s[9],  s[10], s[11]);
        const float a4 = max3f(s[12], s[13], s[14]);
        float pm = fmaxf(max3f(a0, a1, a2), max3f(a3, a4, s[15]));
        pm = fmaxf(pm, __shfl_xor(pm, 32));
        if (__any(pm - mrun > 8.0f)) {     // T13 defer-max rescale
            const float mn = fmaxf(mrun, pm);
            const float al = exp2f(mrun - mn);
            #pragma unroll
            for (int i = 0; i < 16; ++i) { acc[0][i] *= al; acc[1][i] *= al; }
            srun *= al;
            mrun = mn;
        }
        #pragma unroll
        for (int i = 0; i < 16; ++i) s[i] = exp2f(s[i] - mrun);
        // ---- f32 row-sum: pairwise tree + cross-half shfl ----
        {
            const float t0s = s[0]+s[1],  t1s = s[2]+s[3],  t2s = s[4]+s[5],  t3s = s[6]+s[7];
            const float t4s = s[8]+s[9],  t5s = s[10]+s[11], t6s = s[12]+s[13], t7s = s[14]+s[15];
            const float u0 = t0s+t1s, u1 = t2s+t3s, u2 = t4s+t5s, u3 = t6s+t7s;
            float rs = (u0+u1) + (u2+u3);
            rs += __shfl_xor(rs, 32);
            srun += rs;
        }
        // ---- P -> bf16 B-frags via cvt_pk + permlane32_swap (T12; distinct srcs) --
        unsigned w[8];
        #pragma unroll
        for (int j = 0; j < 8; ++j)
            asm("v_cvt_pk_bf16_f32 %0, %1, %2" : "=v"(w[j]) : "v"(s[2*j]), "v"(s[2*j+1]));
        asm volatile("v_permlane32_swap_b32 %0, %1" : "+v"(w[0]), "+v"(w[2]));
        asm volatile("v_permlane32_swap_b32 %0, %1" : "+v"(w[1]), "+v"(w[3]));
        asm volatile("v_permlane32_swap_b32 %0, %1" : "+v"(w[4]), "+v"(w[6]));
        asm volatile("v_permlane32_swap_b32 %0, %1" : "+v"(w[5]), "+v"(w[7]));
        union { uint4 u; short8v s8; } pb0, pb1;
        pb0.u = make_uint4(w[0], w[1], w[2], w[3]);   // k-chain 0..15
        pb1.u = make_uint4(w[4], w[5], w[6], w[7]);   // k-chain 16..31
        // ---- O^T += V^T . P  (4 mfma) ----
        __builtin_amdgcn_s_setprio(1);
        acc[0] = __builtin_amdgcn_mfma_f32_32x32x16_bf16(vf00, pb0.s8, acc[0], 0, 0, 0);
        acc[1] = __builtin_amdgcn_mfma_f32_32x32x16_bf16(vf01, pb0.s8, acc[1], 0, 0, 0);
        acc[0] = __builtin_amdgcn_mfma_f32_32x32x16_bf16(vf10, pb1.s8, acc[0], 0, 0, 0);
        acc[1] = __builtin_amdgcn_mfma_f32_32x32x16_bf16(vf11, pb1.s8, acc[1], 0, 0, 0);
        __builtin_amdgcn_s_setprio(0);
        if (mf) {
            #pragma unroll
            for (int j = 0; j < 8; ++j) mcur[j] = mnxt[j];
        }
    }
    // ---- epilogue: O = acc/srun, packed 8B stores, (B,L,E) row order ----
    const float inv = 1.0f / srun;
    const int b = bh >> 4, h = bh & 15;
    unsigned short* orow = attn_out + ((size_t)(b * LL + qtok)) * EE + h * HD;
    #pragma unroll
    for (int dt = 0; dt < 2; ++dt) {
        #pragma unroll
        for (int g = 0; g < 4; ++g) {
            const float a0 = acc[dt][4*g+0]*inv, a1 = acc[dt][4*g+1]*inv;
            const float a2 = acc[dt][4*g+2]*inv, a3 = acc[dt][4*g+3]*inv;
            unsigned lo, hw;
            asm("v_cvt_pk_bf16_f32 %0, %1, %2" : "=v"(lo) : "v"(a0), "v"(a1));
            asm("v_cvt_pk_bf16_f32 %0, %1, %2" : "=v"(hw) : "v"(a2), "v"(a3));
            *(uint2*)&orow[dt*32 + g*8 + hi*4] = make_uint2(lo, hw);
        }
    }
}

extern "C" void kernel_launch(void* const* d_in, const int* in_sizes, int n_in,
                              void* d_out, int out_size, void* d_ws, size_t ws_size,
                              hipStream_t stream) {
    (void)in_sizes; (void)n_in; (void)out_size; (void)ws_size;
    const float* x     = (const float*)d_in[0];
    const float* mask  = (const float*)d_in[1];
    const float* Wq    = (const float*)d_in[2];
    const float* bq    = (const float*)d_in[3];
    const float* Wk    = (const float*)d_in[4];
    const float* bk    = (const float*)d_in[5];
    const float* Wv    = (const float*)d_in[6];
    const float* bv    = (const float*)d_in[7];
    const float* Wo    = (const float*)d_in[8];
    const float* bo    = (const float*)d_in[9];
    const float* gamma = (const float*)d_in[10];
    const float* beta  = (const float*)d_in[11];
    float* out = (float*)d_out;

    // workspace layout (ushort units); total exactly 72 MiB — no growth allowed
    unsigned short* ws   = (unsigned short*)d_ws;
    unsigned short* ln   = ws;                          // 8192*1024 (B,L,E); reused as attnb
    unsigned short* wqkv = ln   + (size_t)MROWS * EE;   // 3 x 1024 x 1024 (Wq;Wk;Wv)
    unsigned short* wob  = wqkv + (size_t)3 * EE * EE;
    unsigned short* qb   = wob  + (size_t)EE * EE;      // Q fragments
    unsigned short* kbp  = qb   + (size_t)BB * HH * LL * HD;  // K fragments
    unsigned short* vtb  = kbp  + (size_t)BB * HH * LL * HD;  // V fragments
    unsigned short* attnb = ln;                         // reuse after QKV GEMM
    unsigned* maskT2 = (unsigned*)wqkv;                 // reuse wqkv AFTER gemm_qkv (2 MiB)
    unsigned* mflag  = (unsigned*)(wqkv + (size_t)2 * EE * EE);  // +4 MiB into dead region

    convw4_kernel<<<dim3(1024, 4), 256, 0, stream>>>(
        Wq, Wk, Wv, Wo,
        wqkv, wqkv + (size_t)EE * EE, wqkv + (size_t)2 * EE * EE, wob);
    ln_kernel<<<MROWS, 256, 0, stream>>>(x, gamma, beta, ln);

    gemm_qkv<<<768, 256, 0, stream>>>(ln, wqkv, bq, bk, bv, qb, kbp, vtb);

    // wqkv now dead -> mask flag + transposed pair-packed mask in its space
    hipMemsetAsync(mflag, 0, 4, stream);
    maskprep_kernel<<<dim3(16, 16), 256, 0, stream>>>(mask, maskT2, mflag);

    attn_kernel<<<1024, 256, 0, stream>>>(qb, kbp, vtb, maskT2, mflag, attnb);

    gemm_o<<<dim3(8, 64), 256, 0, stream>>>(attnb, wob, bo, x, out);
}

// Round 18
// 195.619 us; speedup vs baseline: 1.0377x; 1.0377x over previous
//
#include <hip/hip_runtime.h>

// Problem dims
#define LL 1024
#define BB 8
#define EE 1024
#define HH 16
#define HD 64
#define MROWS (LL*BB)   // 8192 token rows

typedef __attribute__((ext_vector_type(8))) short short8v;   // 8 bf16 (4 VGPRs)
typedef __attribute__((ext_vector_type(4))) float f32x4;
typedef __attribute__((ext_vector_type(16))) float f32x16;

#define LOG2E 1.44269504088896f

__device__ __forceinline__ unsigned short tobf(float f) {
    union { float f; unsigned u; } un; un.f = f;
    unsigned u = un.u;
    u += 0x7fffu + ((u >> 16) & 1u);   // round-to-nearest-even
    return (unsigned short)(u >> 16);
}

__device__ __forceinline__ float max3f(float a, float b, float c) {
    return fmaxf(fmaxf(a, b), c);      // clang fuses to v_max3_f32
}

__device__ __forceinline__ void load_lds16(const unsigned short* g, unsigned short* l) {
    // async global->LDS, 16B per lane; LDS dest = wave-uniform base + lane*16
    __builtin_amdgcn_global_load_lds((const __attribute__((address_space(1))) unsigned int*)g,
                                     (__attribute__((address_space(3))) unsigned int*)l,
                                     16, 0, 0);
}

// ---------------- weight f32 -> bf16, 4 weights in one launch -----------------
__global__ __launch_bounds__(256) void convw4_kernel(const float* __restrict__ w0,
                                                     const float* __restrict__ w1,
                                                     const float* __restrict__ w2,
                                                     const float* __restrict__ w3,
                                                     unsigned short* __restrict__ o0,
                                                     unsigned short* __restrict__ o1,
                                                     unsigned short* __restrict__ o2,
                                                     unsigned short* __restrict__ o3) {
    const float* w; unsigned short* o;
    switch (blockIdx.y) {
        case 0:  w = w0; o = o0; break;
        case 1:  w = w1; o = o1; break;
        case 2:  w = w2; o = o2; break;
        default: w = w3; o = o3; break;
    }
    int i = (blockIdx.x * 256 + threadIdx.x) * 4;
    float4 v = *(const float4*)&w[i];
    ushort4 r;
    r.x = tobf(v.x); r.y = tobf(v.y); r.z = tobf(v.z); r.w = tobf(v.w);
    *(ushort4*)&o[i] = r;
}

// ---------------- mask prep: maskT2[k2][q] = pack(bf16(mask[q][2k2]*log2e),
//  bf16(mask[q][2k2+1]*log2e)) transposed pair-packed; OR-reduce nonzero flag --
__global__ __launch_bounds__(256) void maskprep_kernel(const float* __restrict__ m,
                                                       unsigned* __restrict__ o,
                                                       unsigned* __restrict__ flag) {
    __shared__ float t_sh[64][65];
    const int q0 = blockIdx.x * 64, k0 = blockIdx.y * 64;
    const int tid = threadIdx.x;
    unsigned nz = 0;
    {
        const int r = tid >> 2, c0 = (tid & 3) * 16;
        #pragma unroll
        for (int i = 0; i < 4; ++i) {
            float4 v = *(const float4*)&m[(size_t)(q0 + r) * LL + k0 + c0 + i*4];
            nz |= (v.x != 0.0f) | (v.y != 0.0f) | (v.z != 0.0f) | (v.w != 0.0f);
            t_sh[r][c0+i*4+0] = v.x; t_sh[r][c0+i*4+1] = v.y;
            t_sh[r][c0+i*4+2] = v.z; t_sh[r][c0+i*4+3] = v.w;
        }
    }
    if (__any(nz) && (tid & 63) == 0) atomicOr(flag, 1u);
    __syncthreads();
    const int k2l = tid >> 3, qi = (tid & 7) * 8;
    unsigned pk[8];
    #pragma unroll
    for (int j = 0; j < 8; ++j) {
        const unsigned lo = tobf(t_sh[qi+j][2*k2l]   * LOG2E);
        const unsigned hb = tobf(t_sh[qi+j][2*k2l+1] * LOG2E);
        pk[j] = lo | (hb << 16);
    }
    unsigned* orow = &o[(size_t)(k0/2 + k2l) * LL + q0 + qi];
    *(uint4*)&orow[0] = make_uint4(pk[0], pk[1], pk[2], pk[3]);
    *(uint4*)&orow[4] = make_uint4(pk[4], pk[5], pk[6], pk[7]);
}

// ---------------- LayerNorm: (L,B,E) in -> (B,L,E) out (token-major rows) ----
__global__ __launch_bounds__(256) void ln_kernel(const float* __restrict__ x,
                                                 const float* __restrict__ gamma,
                                                 const float* __restrict__ beta,
                                                 unsigned short* __restrict__ out) {
    const int row = blockIdx.x;              // (L,B) row: l = row>>3, b = row&7
    const int tid = threadIdx.x;
    const float4 v = *(const float4*)&x[(size_t)row * EE + tid * 4];
    float s = v.x + v.y + v.z + v.w;
    float q = v.x*v.x + v.y*v.y + v.z*v.z + v.w*v.w;
    #pragma unroll
    for (int off = 1; off < 64; off <<= 1) {
        s += __shfl_xor(s, off);
        q += __shfl_xor(q, off);
    }
    __shared__ float ss[4], sq[4];
    const int wv = tid >> 6;
    if ((tid & 63) == 0) { ss[wv] = s; sq[wv] = q; }
    __syncthreads();
    s = ss[0] + ss[1] + ss[2] + ss[3];
    q = sq[0] + sq[1] + sq[2] + sq[3];
    const float mu = s * (1.0f / EE);
    const float var = q * (1.0f / EE) - mu * mu;
    const float rs = rsqrtf(var + 1e-5f);
    ushort4 o;
    o.x = tobf((v.x - mu) * rs * gamma[tid*4+0] + beta[tid*4+0]);
    o.y = tobf((v.y - mu) * rs * gamma[tid*4+1] + beta[tid*4+1]);
    o.z = tobf((v.z - mu) * rs * gamma[tid*4+2] + beta[tid*4+2]);
    o.w = tobf((v.w - mu) * rs * gamma[tid*4+3] + beta[tid*4+3]);
    const int rowBL = (row & 7) * LL + (row >> 3);   // (B,L) row order
    *(ushort4*)&out[(size_t)rowBL * EE + tid * 4] = o;
}

// ---------------- 128x128-tile GEMM, BK=32, 3-buffer counted-vmcnt pipeline ---
// LDS 16B-slot swizzle XORs (row>>2)&3 (write: (lane>>4)&3) — rule #21 involution.
#define GEMM128_BODY(A_, W_)                                                              \
    __shared__ unsigned short a_sh[3][128*32];                                            \
    __shared__ unsigned short b_sh[3][128*32];                                            \
    const int tid = threadIdx.x, lane = tid & 63, wave = tid >> 6;                        \
    const int bm = blockIdx.y * 128, bn = blockIdx.x * 128;                               \
    const int wr = (wave >> 1) * 64, wc = (wave & 1) * 64;                                \
    const int l16 = lane & 15, q4 = lane >> 4;                                            \
    const int grow = lane >> 2;                                                           \
    const int gswz = (((lane & 3) ^ ((lane >> 4) & 3)) * 8);                              \
    const int rslot = (q4 ^ ((l16 >> 2) & 3)) * 16;  /* ds_read byte slot */              \
    f32x4 acc[4][4] = {};                                                                 \
    _Pragma("unroll")                                                                     \
    for (int i = 0; i < 2; ++i) {                                                         \
        const int ch = wave * 2 + i;                                                      \
        load_lds16(&A_[(size_t)(bm + ch*16 + grow)*EE + gswz], &a_sh[0][ch*512]);         \
        load_lds16(&W_[(size_t)(bn + ch*16 + grow)*EE + gswz], &b_sh[0][ch*512]);         \
    }                                                                                     \
    _Pragma("unroll")                                                                     \
    for (int i = 0; i < 2; ++i) {                                                         \
        const int ch = wave * 2 + i;                                                      \
        load_lds16(&A_[(size_t)(bm + ch*16 + grow)*EE + 32 + gswz], &a_sh[1][ch*512]);    \
        load_lds16(&W_[(size_t)(bn + ch*16 + grow)*EE + 32 + gswz], &b_sh[1][ch*512]);    \
    }                                                                                     \
    int buf = 0, sb = 2;                                                                  \
    for (int it = 0; it < 32; ++it) {                                                     \
        if (it < 31) asm volatile("s_waitcnt vmcnt(4)" ::: "memory");                     \
        else         asm volatile("s_waitcnt vmcnt(0)" ::: "memory");                     \
        __builtin_amdgcn_s_barrier();                                                     \
        if (it < 30) {                                                                    \
            const int kn = (it + 2) * 32;                                                 \
            _Pragma("unroll")                                                             \
            for (int i = 0; i < 2; ++i) {                                                 \
                const int ch = wave * 2 + i;                                              \
                load_lds16(&A_[(size_t)(bm + ch*16 + grow)*EE + kn + gswz], &a_sh[sb][ch*512]); \
                load_lds16(&W_[(size_t)(bn + ch*16 + grow)*EE + kn + gswz], &b_sh[sb][ch*512]); \
            }                                                                             \
        }                                                                                 \
        short8v af[4], bf[4];                                                             \
        _Pragma("unroll")                                                                 \
        for (int mi = 0; mi < 4; ++mi)                                                    \
            af[mi] = *(const short8v*)((const char*)&a_sh[buf][0] + (size_t)(wr + mi*16 + l16)*64 + rslot); \
        _Pragma("unroll")                                                                 \
        for (int ni = 0; ni < 4; ++ni)                                                    \
            bf[ni] = *(const short8v*)((const char*)&b_sh[buf][0] + (size_t)(wc + ni*16 + l16)*64 + rslot); \
        __builtin_amdgcn_s_setprio(1);                                                    \
        _Pragma("unroll")                                                                 \
        for (int mi = 0; mi < 4; ++mi)                                                    \
            _Pragma("unroll")                                                             \
            for (int ni = 0; ni < 4; ++ni)                                                \
                acc[mi][ni] = __builtin_amdgcn_mfma_f32_16x16x32_bf16(af[mi], bf[ni], acc[mi][ni], 0, 0, 0); \
        __builtin_amdgcn_s_setprio(0);                                                    \
        buf = (buf == 2) ? 0 : buf + 1;                                                   \
        sb  = (sb  == 2) ? 0 : sb  + 1;                                                   \
    }

// QKV fused: W = [Wq;Wk;Wv] (3072 x 1024); A in (B,L,E) row order.
// m' = b*1024 + token -> consecutive lanes/tokens stay within ONE bh buffer:
// Q/K scalar stores coalesce into 16B chunks; V packs 4 tokens (r=0..3 -> ke)
// into one 8B store.
__global__ __launch_bounds__(256) void gemm_qkv(const unsigned short* __restrict__ A,
                                                const unsigned short* __restrict__ W,
                                                const float* __restrict__ bq,
                                                const float* __restrict__ bk,
                                                const float* __restrict__ bv,
                                                unsigned short* __restrict__ qo,
                                                unsigned short* __restrict__ ko,
                                                unsigned short* __restrict__ vo) {
    GEMM128_BODY(A, W)
    const int seg = blockIdx.x >> 3;
    const float* bias = seg == 0 ? bq : (seg == 1 ? bk : bv);
    #pragma unroll
    for (int mi = 0; mi < 4; ++mi) {
        #pragma unroll
        for (int ni = 0; ni < 4; ++ni) {
            if (seg == 2) {
                // V: pack r=0..3 (consecutive tokens -> consecutive ke) into 8B
                const int m0    = bm + wr + mi*16 + (lane >> 4)*4;   // 4-aligned token base
                const int token = m0 & 1023, b = m0 >> 10;
                const int nn = (bn & 1023) + wc + ni*16 + l16;
                const int d = nn & 63, h = nn >> 6;
                const int bh = b*HH + h;
                const int k16 = token >> 4, khi = (token >> 3) & 1, ke0 = token & 7;
                const int dt = d >> 5, dl = d & 31;
                const float bs = bias[nn];
                ushort4 pk;
                pk.x = tobf(acc[mi][ni][0] + bs);
                pk.y = tobf(acc[mi][ni][1] + bs);
                pk.z = tobf(acc[mi][ni][2] + bs);
                pk.w = tobf(acc[mi][ni][3] + bs);
                *(ushort4*)&vo[((((size_t)bh*64 + k16)*2 + dt)*64 + khi*32 + dl)*8 + ke0] = pk;
            } else {
                #pragma unroll
                for (int r = 0; r < 4; ++r) {
                    const int m  = bm + wr + mi*16 + (lane >> 4)*4 + r;
                    const int token = m & 1023, b = m >> 10;
                    const int nn = (bn & 1023) + wc + ni*16 + l16;
                    const float v = acc[mi][ni][r] + bias[nn];
                    const int d = nn & 63, h = nn >> 6;
                    const int bh = b*HH + h;
                    const int t32 = token >> 5, l32 = token & 31;
                    const int dc = d >> 4, hi2 = (d >> 3) & 1, e = d & 7;
                    const size_t idx = ((((size_t)bh*32 + t32)*4 + dc)*64 + hi2*32 + l32)*8 + e;
                    if (seg == 0) qo[idx] = tobf(v * (0.125f * LOG2E));  // exp2-domain Q
                    else          ko[idx] = tobf(v);
                }
            }
        }
    }
}

// Output projection + bias + residual; A (=attnb) in (B,L,E), out/xres in (L,B,E).
__global__ __launch_bounds__(256) void gemm_o(const unsigned short* __restrict__ A,
                                              const unsigned short* __restrict__ W,
                                              const float* __restrict__ bias,
                                              const float* __restrict__ xres,
                                              float* __restrict__ outf) {
    GEMM128_BODY(A, W)
    #pragma unroll
    for (int mi = 0; mi < 4; ++mi) {
        #pragma unroll
        for (int ni = 0; ni < 4; ++ni) {
            #pragma unroll
            for (int r = 0; r < 4; ++r) {
                const int m = bm + wr + mi*16 + (lane >> 4)*4 + r;   // (B,L) row
                const int token = m & 1023, b = m >> 10;
                const int mout = token * BB + b;                      // (L,B) row
                const int n = bn + wc + ni*16 + l16;
                outf[(size_t)mout * EE + n] = acc[mi][ni][r] + bias[n] + xres[(size_t)mout * EE + n];
            }
        }
    }
}

// ---------------- Flash attention: LDS-free, round-9 structure (verified) ----
__global__ __launch_bounds__(256, 4) void attn_kernel(const unsigned short* __restrict__ Qf,
                                                      const unsigned short* __restrict__ Kf,
                                                      const unsigned short* __restrict__ Vf,
                                                      const unsigned* __restrict__ maskT2,
                                                      const unsigned* __restrict__ mflagp,
                                                      unsigned short* __restrict__ attn_out) {
    const int tid = threadIdx.x, lane = tid & 63, wave = tid >> 6;
    const int l32 = lane & 31, hi = lane >> 5;
    const int b1 = blockIdx.x;
    const int bh = (b1 & 7) * 16 + ((b1 >> 3) & 15);   // all 8 blocks of bh -> same XCD
    const int qt = ((b1 >> 7) & 7) * 4 + wave;          // 32-token q tile
    const int qtok = qt * 32 + l32;
    const unsigned mf = (unsigned)__builtin_amdgcn_readfirstlane((int)mflagp[0]);
    const unsigned short* qfp = Qf + ((size_t)(bh * 32 + qt) * 4) * 512;
    const unsigned short* kfb = Kf + (size_t)bh * 32 * 4 * 512;
    const unsigned short* vfb = Vf + (size_t)bh * 64 * 2 * 512;

    short8v qf[4];
    #pragma unroll
    for (int dc = 0; dc < 4; ++dc)
        qf[dc] = *(const short8v*)&qfp[dc * 512 + lane * 8];

    f32x16 acc[2] = {};           // O^T accumulator: dt=0 (d 0..31), dt=1 (d 32..63)
    float mrun = -1e30f, srun = 0.f;

    const unsigned* mt2base = maskT2 + qtok;
    short8v kf[4];
    #pragma unroll
    for (int dc = 0; dc < 4; ++dc)
        kf[dc] = *(const short8v*)&kfb[dc * 512 + lane * 8];
    unsigned mcur[8], mnxt[8];
    if (mf) {
        #pragma unroll
        for (int j = 0; j < 8; ++j)
            mcur[j] = mt2base[(size_t)((j & 1) + 4*(j >> 1) + 2*hi) * LL];
    }

    for (int t = 0; t < 32; ++t) {
        // ---- S^T = K . Q^T over d=64 (4 chained mfma) ----
        f32x16 s = {};
        __builtin_amdgcn_s_setprio(1);
        #pragma unroll
        for (int dc = 0; dc < 4; ++dc)
            s = __builtin_amdgcn_mfma_f32_32x32x16_bf16(kf[dc], qf[dc], s, 0, 0, 0);
        __builtin_amdgcn_s_setprio(0);
        // ---- prefetch: this tile's V frags, next tile's K frags + mask ----
        short8v vf00, vf01, vf10, vf11;   // [ks][dt]
        vf00 = *(const short8v*)&vfb[((size_t)(t*2 + 0)*2 + 0)*512 + lane*8];
        vf01 = *(const short8v*)&vfb[((size_t)(t*2 + 0)*2 + 1)*512 + lane*8];
        vf10 = *(const short8v*)&vfb[((size_t)(t*2 + 1)*2 + 0)*512 + lane*8];
        vf11 = *(const short8v*)&vfb[((size_t)(t*2 + 1)*2 + 1)*512 + lane*8];
        if (t < 31) {
            #pragma unroll
            for (int dc = 0; dc < 4; ++dc)
                kf[dc] = *(const short8v*)&kfb[((size_t)(t + 1)*4 + dc)*512 + lane*8];
            if (mf) {
                #pragma unroll
                for (int j = 0; j < 8; ++j)
                    mnxt[j] = mt2base[(size_t)((t + 1)*16 + (j & 1) + 4*(j >> 1) + 2*hi) * LL];
            }
        }
        // ---- mask add (skipped entirely when mask is all-zero) ----
        if (mf) {
            #pragma unroll
            for (int j = 0; j < 8; ++j) {
                s[2*j]   += __uint_as_float(mcur[j] << 16);
                s[2*j+1] += __uint_as_float(mcur[j] & 0xffff0000u);
            }
        }
        // ---- max (tree + cross-half shfl) ----
        const float a0 = max3f(s[0],  s[1],  s[2]);
        const float a1 = max3f(s[3],  s[4],  s[5]);
        const float a2 = max3f(s[6],  s[7],  s[8]);
        const float a3 = max3f(s[9],  s[10], s[11]);
        const float a4 = max3f(s[12], s[13], s[14]);
        float pm = fmaxf(max3f(a0, a1, a2), max3f(a3, a4, s[15]));
        pm = fmaxf(pm, __shfl_xor(pm, 32));
        if (__any(pm - mrun > 8.0f)) {     // T13 defer-max rescale
            const float mn = fmaxf(mrun, pm);
            const float al = exp2f(mrun - mn);
            #pragma unroll
            for (int i = 0; i < 16; ++i) { acc[0][i] *= al; acc[1][i] *= al; }
            srun *= al;
            mrun = mn;
        }
        #pragma unroll
        for (int i = 0; i < 16; ++i) s[i] = exp2f(s[i] - mrun);
        // ---- f32 row-sum: pairwise tree + cross-half shfl ----
        {
            const float t0s = s[0]+s[1],  t1s = s[2]+s[3],  t2s = s[4]+s[5],  t3s = s[6]+s[7];
            const float t4s = s[8]+s[9],  t5s = s[10]+s[11], t6s = s[12]+s[13], t7s = s[14]+s[15];
            const float u0 = t0s+t1s, u1 = t2s+t3s, u2 = t4s+t5s, u3 = t6s+t7s;
            float rs = (u0+u1) + (u2+u3);
            rs += __shfl_xor(rs, 32);
            srun += rs;
        }
        // ---- P -> bf16 B-frags via cvt_pk + permlane32_swap (T12; distinct srcs) --
        unsigned w[8];
        #pragma unroll
        for (int j = 0; j < 8; ++j)
            asm("v_cvt_pk_bf16_f32 %0, %1, %2" : "=v"(w[j]) : "v"(s[2*j]), "v"(s[2*j+1]));
        asm volatile("v_permlane32_swap_b32 %0, %1" : "+v"(w[0]), "+v"(w[2]));
        asm volatile("v_permlane32_swap_b32 %0, %1" : "+v"(w[1]), "+v"(w[3]));
        asm volatile("v_permlane32_swap_b32 %0, %1" : "+v"(w[4]), "+v"(w[6]));
        asm volatile("v_permlane32_swap_b32 %0, %1" : "+v"(w[5]), "+v"(w[7]));
        union { uint4 u; short8v s8; } pb0, pb1;
        pb0.u = make_uint4(w[0], w[1], w[2], w[3]);   // k-chain 0..15
        pb1.u = make_uint4(w[4], w[5], w[6], w[7]);   // k-chain 16..31
        // ---- O^T += V^T . P  (4 mfma) ----
        __builtin_amdgcn_s_setprio(1);
        acc[0] = __builtin_amdgcn_mfma_f32_32x32x16_bf16(vf00, pb0.s8, acc[0], 0, 0, 0);
        acc[1] = __builtin_amdgcn_mfma_f32_32x32x16_bf16(vf01, pb0.s8, acc[1], 0, 0, 0);
        acc[0] = __builtin_amdgcn_mfma_f32_32x32x16_bf16(vf10, pb1.s8, acc[0], 0, 0, 0);
        acc[1] = __builtin_amdgcn_mfma_f32_32x32x16_bf16(vf11, pb1.s8, acc[1], 0, 0, 0);
        __builtin_amdgcn_s_setprio(0);
        if (mf) {
            #pragma unroll
            for (int j = 0; j < 8; ++j) mcur[j] = mnxt[j];
        }
    }
    // ---- epilogue: O = acc/srun, packed 8B stores, (B,L,E) row order ----
    const float inv = 1.0f / srun;
    const int b = bh >> 4, h = bh & 15;
    unsigned short* orow = attn_out + ((size_t)(b * LL + qtok)) * EE + h * HD;
    #pragma unroll
    for (int dt = 0; dt < 2; ++dt) {
        #pragma unroll
        for (int g = 0; g < 4; ++g) {
            const float a0 = acc[dt][4*g+0]*inv, a1 = acc[dt][4*g+1]*inv;
            const float a2 = acc[dt][4*g+2]*inv, a3 = acc[dt][4*g+3]*inv;
            unsigned lo, hw;
            asm("v_cvt_pk_bf16_f32 %0, %1, %2" : "=v"(lo) : "v"(a0), "v"(a1));
            asm("v_cvt_pk_bf16_f32 %0, %1, %2" : "=v"(hw) : "v"(a2), "v"(a3));
            *(uint2*)&orow[dt*32 + g*8 + hi*4] = make_uint2(lo, hw);
        }
    }
}

extern "C" void kernel_launch(void* const* d_in, const int* in_sizes, int n_in,
                              void* d_out, int out_size, void* d_ws, size_t ws_size,
                              hipStream_t stream) {
    (void)in_sizes; (void)n_in; (void)out_size; (void)ws_size;
    const float* x     = (const float*)d_in[0];
    const float* mask  = (const float*)d_in[1];
    const float* Wq    = (const float*)d_in[2];
    const float* bq    = (const float*)d_in[3];
    const float* Wk    = (const float*)d_in[4];
    const float* bk    = (const float*)d_in[5];
    const float* Wv    = (const float*)d_in[6];
    const float* bv    = (const float*)d_in[7];
    const float* Wo    = (const float*)d_in[8];
    const float* bo    = (const float*)d_in[9];
    const float* gamma = (const float*)d_in[10];
    const float* beta  = (const float*)d_in[11];
    float* out = (float*)d_out;

    // workspace layout (ushort units); total exactly 72 MiB — no growth allowed
    unsigned short* ws   = (unsigned short*)d_ws;
    unsigned short* ln   = ws;                          // 8192*1024 (B,L,E); reused as attnb
    unsigned short* wqkv = ln   + (size_t)MROWS * EE;   // 3 x 1024 x 1024 (Wq;Wk;Wv)
    unsigned short* wob  = wqkv + (size_t)3 * EE * EE;
    unsigned short* qb   = wob  + (size_t)EE * EE;      // Q fragments
    unsigned short* kbp  = qb   + (size_t)BB * HH * LL * HD;  // K fragments
    unsigned short* vtb  = kbp  + (size_t)BB * HH * LL * HD;  // V fragments
    unsigned short* attnb = ln;                         // reuse after QKV GEMM
    unsigned* maskT2 = (unsigned*)wqkv;                 // reuse wqkv AFTER gemm_qkv (2 MiB)
    unsigned* mflag  = (unsigned*)(wqkv + (size_t)2 * EE * EE);  // +4 MiB into dead region

    convw4_kernel<<<dim3(1024, 4), 256, 0, stream>>>(
        Wq, Wk, Wv, Wo,
        wqkv, wqkv + (size_t)EE * EE, wqkv + (size_t)2 * EE * EE, wob);
    ln_kernel<<<MROWS, 256, 0, stream>>>(x, gamma, beta, ln);

    gemm_qkv<<<dim3(24, 64), 256, 0, stream>>>(ln, wqkv, bq, bk, bv, qb, kbp, vtb);

    // wqkv now dead -> mask flag + transposed pair-packed mask in its space
    hipMemsetAsync(mflag, 0, 4, stream);
    maskprep_kernel<<<dim3(16, 16), 256, 0, stream>>>(mask, maskT2, mflag);

    attn_kernel<<<1024, 256, 0, stream>>>(qb, kbp, vtb, maskT2, mflag, attnb);

    gemm_o<<<dim3(8, 64), 256, 0, stream>>>(attnb, wob, bo, x, out);
}